// Round 4
// baseline (3932.534 us; speedup 1.0000x reference)
//
#include <hip/hip_runtime.h>
#include <stdint.h>
#include <math.h>

typedef __attribute__((ext_vector_type(8))) short short8;
typedef __attribute__((ext_vector_type(4))) short short4v;
typedef __attribute__((ext_vector_type(4))) float f32x4;

#define NBLK 256

__device__ __forceinline__ short f2bf(float f){
  union { float f; uint32_t u; } x; x.f = f;
  uint32_t r = x.u + 0x7fffu + ((x.u >> 16) & 1u);
  return (short)(r >> 16);
}
__device__ __forceinline__ float bf2f(short s){
  union { uint32_t u; float f; } x; x.u = ((uint32_t)(uint16_t)s) << 16;
  return x.f;
}

// grid barrier: monotonic counter, agent scope. All 256 blocks co-resident
// (grid == CU count, 1 block/CU by resource usage).
__device__ __forceinline__ void gbar(unsigned* cnt, unsigned target){
  __syncthreads();
  if (threadIdx.x == 0){
    __threadfence();
    __hip_atomic_fetch_add(cnt, 1u, __ATOMIC_RELAXED, __HIP_MEMORY_SCOPE_AGENT);
    while (__hip_atomic_load(cnt, __ATOMIC_RELAXED, __HIP_MEMORY_SCOPE_AGENT) < target)
      __builtin_amdgcn_s_sleep(2);
    __threadfence();
  }
  __syncthreads();
}

// ---------------- prep kernels ----------------

// Transposed, bf16, concatenated weights: W3T[j][k], j in [0,4096), k in [0,3072)
__global__ __launch_bounds__(256) void k_wt(const float* __restrict__ Wx,
                                            const float* __restrict__ Wh,
                                            const float* __restrict__ Wattn,
                                            short* __restrict__ W3T){
  __shared__ float tile[64][65];
  int bk = blockIdx.x % 48, bj = blockIdx.x / 48;
  int tx = threadIdx.x & 63, ty = threadIdx.x >> 6;
  int k0 = bk * 64, j0 = bj * 64;
  #pragma unroll
  for (int i = 0; i < 16; ++i){
    int kk = ty * 16 + i;
    int k = k0 + kk;
    const float* src = (k < 1024) ? (Wx + (size_t)k * 4096)
                     : (k < 2048) ? (Wh + (size_t)(k - 1024) * 4096)
                                  : (Wattn + (size_t)(k - 2048) * 4096);
    tile[kk][tx] = src[j0 + tx];
  }
  __syncthreads();
  #pragma unroll
  for (int i = 0; i < 16; ++i){
    int jj = ty * 16 + i;
    W3T[(size_t)(j0 + jj) * 3072 + k0 + tx] = f2bf(tile[tx][jj]);
  }
}

__global__ __launch_bounds__(256) void k_cast(const float* __restrict__ in,
                                              short* __restrict__ out, int n4){
  int i = blockIdx.x * 256 + threadIdx.x;
  if (i >= n4) return;
  float4 v = ((const float4*)in)[i];
  short4v o; o[0] = f2bf(v.x); o[1] = f2bf(v.y); o[2] = f2bf(v.z); o[3] = f2bf(v.w);
  *(short4v*)(out + (size_t)i * 4) = o;
}

// h0 = c0 = mean over L=16 of A; also zero the barrier counter
__global__ __launch_bounds__(256) void k_init(const float* __restrict__ A,
                                              float* __restrict__ c,
                                              short* __restrict__ hb0,
                                              unsigned* __restrict__ barcnt){
  int idx = blockIdx.x * 256 + threadIdx.x;    // N*H = 131072
  if (idx == 0) *barcnt = 0u;
  const float* p = A + (size_t)idx * 16;
  float s = 0.f;
  #pragma unroll
  for (int l = 0; l < 16; ++l) s += p[l];
  s *= (1.f / 16.f);
  c[idx] = s;
  hb0[idx] = f2bf(s);
}

// ---------------- persistent recurrence kernel ----------------
// 256 blocks x 512 threads, 1 block/CU. Block tile: 64 n (nh half) x 32 j
// (4 gates x 8 u at u0). 8 waves = 8-way K-split (384 each). W slice lives in
// registers (wreg[12][2], 96 VGPR/lane) for all 64 steps. c in registers.
__global__ __launch_bounds__(512, 2) void k_loop(
    const short* __restrict__ W3T,
    const short* __restrict__ xbf,     // [128][64][1024] bf16
    const short* __restrict__ Abf,     // [128][1024][16] bf16
    short* __restrict__ hbuf,          // [2][128][1024] bf16
    short* __restrict__ abuf,          // [128][1024] bf16
    const float* __restrict__ cbuf,    // [128][1024] f32
    const float* __restrict__ bias,    // [4096]
    float* __restrict__ out,           // [128][64][1024] f32
    unsigned* __restrict__ barcnt)
{
  const int tid  = threadIdx.x;
  const int lane = tid & 63;
  const int wave = tid >> 6;           // 0..7 = K-chunk
  const int bid  = blockIdx.x;         // 0..255
  const int ut   = bid >> 1;           // 0..127
  const int nh   = bid & 1;            // n-half
  const int u0   = ut * 8;
  const int n0   = nh * 64;
  const int ra   = lane & 15;
  const int q    = lane >> 4;
  const int kb   = wave * 384;

  // ---- W prologue: two j-fragments (gates 0,1 / gates 2,3), 12 k-steps
  const int jr0 = ((ra >> 3)) * 1024 + u0 + (ra & 7);
  const int jr1 = (2 + (ra >> 3)) * 1024 + u0 + (ra & 7);
  short8 wreg[12][2];
  #pragma unroll
  for (int kk = 0; kk < 12; ++kk){
    wreg[kk][0] = *(const short8*)(W3T + (size_t)jr0 * 3072 + kb + kk * 32 + q * 8);
    wreg[kk][1] = *(const short8*)(W3T + (size_t)jr1 * 3072 + kb + kk * 32 + q * 8);
  }

  // ---- per-thread LSTM cell (n,u) and its state
  const int cn = n0 + (tid >> 3);
  const int cu = u0 + (tid & 7);
  float creg = cbuf[cn * 1024 + cu];
  const float bi  = bias[cu];
  const float bf_ = bias[1024 + cu];
  const float bo  = bias[2048 + cu];
  const float bg  = bias[3072 + cu];

  __shared__ float red[8][2][16][68];  // [wave][f][ra][n + pad]  ~69.6 KB
  __shared__ float sred[8][16];

  unsigned phase = 0;

  for (int t = 0; t < 64; ++t){
    const short* hR = hbuf + (size_t)(t & 1) * 131072;
    short*       hW = hbuf + (size_t)((t + 1) & 1) * 131072;

    // ---------- phase A: attention weights + attn vector (blocks 0..127)
    short8 a00, a01, a10, a11; float h0v = 0.f, h1v = 0.f;
    if (bid < 128){
      const int n = bid;
      h0v = bf2f(hR[n * 1024 + tid * 2 + 0]);
      h1v = bf2f(hR[n * 1024 + tid * 2 + 1]);
      const short8* ap0 = (const short8*)(Abf + ((size_t)n * 1024 + tid * 2 + 0) * 16);
      const short8* ap1 = (const short8*)(Abf + ((size_t)n * 1024 + tid * 2 + 1) * 16);
      a00 = ap0[0]; a01 = ap0[1]; a10 = ap1[0]; a11 = ap1[1];
      float sc[16];
      #pragma unroll
      for (int l = 0; l < 8; ++l){
        sc[l]     = h0v * bf2f(a00[l]) + h1v * bf2f(a10[l]);
        sc[8 + l] = h0v * bf2f(a01[l]) + h1v * bf2f(a11[l]);
      }
      #pragma unroll
      for (int off = 1; off < 64; off <<= 1)
        #pragma unroll
        for (int l = 0; l < 16; ++l) sc[l] += __shfl_xor(sc[l], off);
      if (lane == 0)
        #pragma unroll
        for (int l = 0; l < 16; ++l) sred[wave][l] = sc[l];
    }
    __syncthreads();
    if (bid < 128){
      const int n = bid;
      float s[16], mx = -1e30f, sum = 0.f;
      #pragma unroll
      for (int l = 0; l < 16; ++l){
        float v = sred[0][l];
        #pragma unroll
        for (int w = 1; w < 8; ++w) v += sred[w][l];
        s[l] = v * 0.03125f;
        mx = fmaxf(mx, s[l]);
      }
      #pragma unroll
      for (int l = 0; l < 16; ++l){ s[l] = __expf(s[l] - mx); sum += s[l]; }
      const float inv = 1.f / sum;
      float ac0 = 0.f, ac1 = 0.f;
      #pragma unroll
      for (int l = 0; l < 8; ++l){
        ac0 += s[l] * bf2f(a00[l]) + s[8 + l] * bf2f(a01[l]);
        ac1 += s[l] * bf2f(a10[l]) + s[8 + l] * bf2f(a11[l]);
      }
      abuf[n * 1024 + tid * 2 + 0] = f2bf(ac0 * inv);
      abuf[n * 1024 + tid * 2 + 1] = f2bf(ac1 * inv);
    }
    gbar(barcnt, ++phase * NBLK);     // barA: attn visible everywhere

    // ---------- phase B: GEMM (wave K-chunk) + LDS reduce + LSTM update
    f32x4 acc[4][2];
    #pragma unroll
    for (int m = 0; m < 4; ++m){
      acc[m][0] = f32x4{0.f,0.f,0.f,0.f};
      acc[m][1] = f32x4{0.f,0.f,0.f,0.f};
    }

    auto loadA = [&](int kk, int m) -> short8 {
      const int k = kb + kk * 32 + q * 8;
      const int row = n0 + m * 16 + ra;
      const short* p = (k < 1024) ? (xbf + (size_t)row * 65536 + t * 1024 + k)
                     : (k < 2048) ? (hR + (size_t)row * 1024 + (k - 1024))
                                  : (abuf + (size_t)row * 1024 + (k - 2048));
      return *(const short8*)p;
    };

    short8 ac[4], an[4];
    #pragma unroll
    for (int m = 0; m < 4; ++m) ac[m] = loadA(0, m);
    #pragma unroll
    for (int kk = 0; kk < 12; ++kk){
      if (kk < 11){
        #pragma unroll
        for (int m = 0; m < 4; ++m) an[m] = loadA(kk + 1, m);
      }
      #pragma unroll
      for (int m = 0; m < 4; ++m){
        acc[m][0] = __builtin_amdgcn_mfma_f32_16x16x32_bf16(ac[m], wreg[kk][0], acc[m][0], 0, 0, 0);
        acc[m][1] = __builtin_amdgcn_mfma_f32_16x16x32_bf16(ac[m], wreg[kk][1], acc[m][1], 0, 0, 0);
      }
      if (kk < 11){
        #pragma unroll
        for (int m = 0; m < 4; ++m) ac[m] = an[m];
      }
    }

    #pragma unroll
    for (int m = 0; m < 4; ++m){
      *(f32x4*)&red[wave][0][ra][m * 16 + q * 4] = acc[m][0];
      *(f32x4*)&red[wave][1][ra][m * 16 + q * 4] = acc[m][1];
    }
    __syncthreads();

    {
      const int nl = tid >> 3, uu = tid & 7;
      float gs[4];
      #pragma unroll
      for (int g = 0; g < 4; ++g){
        const int f = g >> 1, jj = (g & 1) * 8 + uu;
        float v = red[0][f][jj][nl];
        #pragma unroll
        for (int w = 1; w < 8; ++w) v += red[w][f][jj][nl];
        gs[g] = v;
      }
      const float av = gs[0] + bi,  fv = gs[1] + bf_;
      const float ov = gs[2] + bo,  gv = gs[3] + bg;
      const float ig = 1.f / (1.f + __expf(-av));
      const float fg = 1.f / (1.f + __expf(-fv));
      const float og = 1.f / (1.f + __expf(-ov));
      const float gcl = fminf(fmaxf(gv, -20.f), 20.f);
      const float e2g = __expf(2.f * gcl);
      const float gg = (e2g - 1.f) / (e2g + 1.f);
      creg = fg * creg + ig * gg;
      const float ccl = fminf(fmaxf(creg, -20.f), 20.f);
      const float e2c = __expf(2.f * ccl);
      const float th = (e2c - 1.f) / (e2c + 1.f);
      const float hn = og * th;
      hW[cn * 1024 + cu] = f2bf(hn);
      __builtin_nontemporal_store(hn, &out[((size_t)cn * 64 + t) * 1024 + cu]);
    }
    if (t < 63) gbar(barcnt, ++phase * NBLK);   // barB: h(t+1) visible
  }
}

// ---------------- launch ----------------

extern "C" void kernel_launch(void* const* d_in, const int* in_sizes, int n_in,
                              void* d_out, int out_size, void* d_ws, size_t ws_size,
                              hipStream_t stream)
{
  const float* x     = (const float*)d_in[0];
  const float* A     = (const float*)d_in[1];
  const float* Wx    = (const float*)d_in[2];
  const float* Wh    = (const float*)d_in[3];
  const float* Wattn = (const float*)d_in[4];
  const float* b     = (const float*)d_in[5];
  float* out = (float*)d_out;
  char* ws = (char*)d_ws;

  short*    W3T    = (short*)(ws + 0);            // 25165824
  short*    Abf    = (short*)(ws + 25165824);     //  4194304
  short*    xbf    = (short*)(ws + 29360128);     // 16777216
  short*    hbuf   = (short*)(ws + 46137344);     //   524288 (2 parities)
  short*    abuf   = (short*)(ws + 46661632);     //   262144
  float*    cbuf   = (float*)(ws + 46923776);     //   524288
  unsigned* barcnt = (unsigned*)(ws + 47448064);  //        4

  hipLaunchKernelGGL(k_wt,   dim3(48 * 64), dim3(256), 0, stream, Wx, Wh, Wattn, W3T);
  hipLaunchKernelGGL(k_cast, dim3(2097152 / 256), dim3(256), 0, stream, x, xbf, 2097152);
  hipLaunchKernelGGL(k_cast, dim3(524288 / 256),  dim3(256), 0, stream, A, Abf, 524288);
  hipLaunchKernelGGL(k_init, dim3(512), dim3(256), 0, stream, A, cbuf, hbuf, barcnt);
  hipLaunchKernelGGL(k_loop, dim3(256), dim3(512), 0, stream,
                     W3T, xbf, Abf, hbuf, abuf, cbuf, b, out, barcnt);
}